// Round 1
// baseline (466.355 us; speedup 1.0000x reference)
//
#include <hip/hip_runtime.h>

#define B_   32
#define T_   512
#define D_   512
#define F_   256
#define MEL  4096
#define EPS_ 1e-5f

// Fused conv1d(K=3, SAME) + bias + LayerNorm + ReLU.
// One block = 256 threads (one per output feature f), TT output rows (t values).
// x rows staged in LDS; weights streamed from L2 (reused TT times per load).
template<int IN_D, int TT>
__global__ __launch_bounds__(256)
void conv_ln_relu_kernel(const float* __restrict__ x, const float* __restrict__ w,
                         const float* __restrict__ bias, const float* __restrict__ gamma,
                         const float* __restrict__ beta, float* __restrict__ out)
{
    __shared__ float xs[(TT + 2) * IN_D];
    __shared__ float red[TT * 8];

    const int f = threadIdx.x;                       // 0..255 output feature
    const int blocksPerBatch = T_ / TT;
    const int b  = blockIdx.x / blocksPerBatch;
    const int t0 = (blockIdx.x % blocksPerBatch) * TT;

    // Stage rows t0-1 .. t0+TT (zero-padded at sequence boundaries).
    const int totalElems = (TT + 2) * IN_D;
    for (int e = threadIdx.x * 4; e < totalElems; e += 256 * 4) {
        int j = e / IN_D;
        int d = e % IN_D;
        int t = t0 - 1 + j;
        float4 v = make_float4(0.f, 0.f, 0.f, 0.f);
        if (t >= 0 && t < T_)
            v = *reinterpret_cast<const float4*>(&x[((size_t)b * T_ + t) * IN_D + d]);
        *reinterpret_cast<float4*>(&xs[e]) = v;
    }
    __syncthreads();

    float acc[TT];
#pragma unroll
    for (int tt = 0; tt < TT; ++tt) acc[tt] = 0.f;

    const int KIN = 3 * IN_D;
    for (int i = 0; i < KIN; i += 4) {
        float w0 = w[(size_t)(i + 0) * F_ + f];
        float w1v = w[(size_t)(i + 1) * F_ + f];
        float w2v = w[(size_t)(i + 2) * F_ + f];
        float w3v = w[(size_t)(i + 3) * F_ + f];
#pragma unroll
        for (int tt = 0; tt < TT; ++tt) {
            // input element i = k*IN_D + d maps to xs[(tt+k)*IN_D + d] = xs[tt*IN_D + i]
            float4 xv = *reinterpret_cast<const float4*>(&xs[tt * IN_D + i]);
            acc[tt] = fmaf(xv.x, w0, acc[tt]);
            acc[tt] = fmaf(xv.y, w1v, acc[tt]);
            acc[tt] = fmaf(xv.z, w2v, acc[tt]);
            acc[tt] = fmaf(xv.w, w3v, acc[tt]);
        }
    }

    const float bv = bias[f];
    const int lane = threadIdx.x & 63;
    const int wid  = threadIdx.x >> 6;

#pragma unroll
    for (int tt = 0; tt < TT; ++tt) {
        float v = acc[tt] + bv;
        acc[tt] = v;
        float s = v, s2 = v * v;
#pragma unroll
        for (int o = 32; o; o >>= 1) {
            s  += __shfl_down(s,  o);
            s2 += __shfl_down(s2, o);
        }
        if (lane == 0) { red[tt * 8 + wid * 2] = s; red[tt * 8 + wid * 2 + 1] = s2; }
    }
    __syncthreads();

    const float gv = gamma[f], bev = beta[f];
#pragma unroll
    for (int tt = 0; tt < TT; ++tt) {
        float s  = red[tt * 8 + 0] + red[tt * 8 + 2] + red[tt * 8 + 4] + red[tt * 8 + 6];
        float s2 = red[tt * 8 + 1] + red[tt * 8 + 3] + red[tt * 8 + 5] + red[tt * 8 + 7];
        float mu  = s * (1.f / F_);
        float var = s2 * (1.f / F_) - mu * mu;
        float rs  = rsqrtf(var + EPS_);
        float y = (acc[tt] - mu) * rs * gv + bev;
        y = fmaxf(y, 0.f);
        out[((size_t)b * T_ + t0 + tt) * F_ + f] = y;
    }
}

// dur_pred = relu(h2 @ wl + bl); one wave per (b,t) row.
__global__ __launch_bounds__(256)
void dur_kernel(const float* __restrict__ h2, const float* __restrict__ wl,
                const float* __restrict__ bl, float* __restrict__ dur)
{
    int lane = threadIdx.x & 63, wid = threadIdx.x >> 6;
    int row = blockIdx.x * 4 + wid;          // < B_*T_
    float4 hv = *reinterpret_cast<const float4*>(&h2[(size_t)row * F_ + lane * 4]);
    float4 wv = *reinterpret_cast<const float4*>(&wl[lane * 4]);
    float s = hv.x * wv.x + hv.y * wv.y + hv.z * wv.z + hv.w * wv.w;
#pragma unroll
    for (int o = 32; o; o >>= 1) s += __shfl_down(s, o);
    if (lane == 0) dur[row] = fmaxf(s + bl[0], 0.f);
}

// Per-batch inclusive cumsum of target (tiny: 32 x 512 ints).
__global__ void cumsum_kernel(const int* __restrict__ tgt, int* __restrict__ cum)
{
    int b = threadIdx.x;
    if (b >= B_) return;
    int run = 0;
    for (int t = 0; t < T_; ++t) { run += tgt[b * T_ + t]; cum[b * T_ + t] = run; }
}

// Length-regulator gather: one wave per output (b,pos) row; binary search cum.
__global__ __launch_bounds__(256)
void gather_kernel(const float* __restrict__ x, const int* __restrict__ cum,
                   float* __restrict__ out)
{
    int lane = threadIdx.x & 63, wid = threadIdx.x >> 6;
    int r = blockIdx.x * 4 + wid;            // 0 .. B_*MEL-1
    int b   = r >> 12;                       // / MEL (4096)
    int pos = r & (MEL - 1);
    const int* c = cum + b * T_;
    int total = c[T_ - 1];

    float4 v0 = make_float4(0.f, 0.f, 0.f, 0.f), v1 = v0;
    if (pos < total) {
        // idx = searchsorted(c, pos, 'right') = first j with c[j] > pos
        int lo = 0, hi = T_;
        while (lo < hi) { int mid = (lo + hi) >> 1; if (c[mid] <= pos) lo = mid + 1; else hi = mid; }
        int idx = min(lo, T_ - 1);
        const float* src = x + ((size_t)b * T_ + idx) * D_ + lane * 8;
        v0 = *reinterpret_cast<const float4*>(src);
        v1 = *reinterpret_cast<const float4*>(src + 4);
    }
    float* dst = out + (size_t)r * D_ + lane * 8;
    *reinterpret_cast<float4*>(dst)     = v0;
    *reinterpret_cast<float4*>(dst + 4) = v1;
}

extern "C" void kernel_launch(void* const* d_in, const int* in_sizes, int n_in,
                              void* d_out, int out_size, void* d_ws, size_t ws_size,
                              hipStream_t stream)
{
    const float* x      = (const float*)d_in[0];
    const int*   target = (const int*)d_in[1];
    // d_in[2] = mel_max_length (compile-time MEL = 4096)
    const float* w1  = (const float*)d_in[3];
    const float* b1  = (const float*)d_in[4];
    const float* g1  = (const float*)d_in[5];
    const float* be1 = (const float*)d_in[6];
    const float* w2  = (const float*)d_in[7];
    const float* b2  = (const float*)d_in[8];
    const float* g2  = (const float*)d_in[9];
    const float* be2 = (const float*)d_in[10];
    const float* wl  = (const float*)d_in[11];
    const float* bl  = (const float*)d_in[12];

    float* out = (float*)d_out;                       // (B, MEL, D)
    float* dur = out + (size_t)B_ * MEL * D_;         // (B, T)

    float* h1  = (float*)d_ws;                        // (B*T, F)
    float* h2  = h1 + (size_t)B_ * T_ * F_;           // (B*T, F)
    int*   cum = (int*)(h2 + (size_t)B_ * T_ * F_);   // (B, T)

    constexpr int TT = 16;
    conv_ln_relu_kernel<D_, TT><<<B_ * (T_ / TT), 256, 0, stream>>>(x,  w1, b1, g1, be1, h1);
    conv_ln_relu_kernel<F_, TT><<<B_ * (T_ / TT), 256, 0, stream>>>(h1, w2, b2, g2, be2, h2);
    dur_kernel<<<(B_ * T_) / 4, 256, 0, stream>>>(h2, wl, bl, dur);
    cumsum_kernel<<<1, 32, 0, stream>>>(target, cum);
    gather_kernel<<<(B_ * MEL) / 4, 256, 0, stream>>>(x, cum, out);
}

// Round 3
// 164.961 us; speedup vs baseline: 2.8271x; 2.8271x over previous
//
#include <hip/hip_runtime.h>
#include <type_traits>

#define B_   32
#define T_   512
#define D_   512
#define F_   256
#define MEL  4096
#define EPS_ 1e-5f

typedef __attribute__((ext_vector_type(8))) short bf16x8;
typedef __attribute__((ext_vector_type(4))) float f32x4;

__device__ inline unsigned short f2bf(float f) {
    unsigned u = __float_as_uint(f);
    unsigned r = (u + 0x7fff + ((u >> 16) & 1)) >> 16;   // RNE
    return (unsigned short)r;
}
__device__ inline float bf2f(unsigned short u) {
    return __uint_as_float(((unsigned)u) << 16);
}

// Transpose + convert weights: w[κ][f] f32 -> wT[f][κ] bf16.
__global__ void prep_w_kernel(const float* __restrict__ w, unsigned short* __restrict__ wT,
                              int KT)
{
    int idx = blockIdx.x * 256 + threadIdx.x;
    if (idx >= KT * F_) return;
    int kk = idx / F_;
    int f  = idx % F_;
    wT[(size_t)f * KT + kk] = f2bf(w[idx]);
}

// Fused conv1d(K=3,SAME) + bias + LayerNorm + ReLU via bf16 MFMA.
// Block: 256 thr (4 waves); tile MT=32 output rows x all 256 f. Wave wv owns f in [wv*64, wv*64+64).
// A (im2col rows t0-1..t0+MT of x) staged once in LDS bf16, XOR-swizzled (T2) against the
// IN_D*2-byte row-stride bank conflict; B fragments stream from L2 (wT is 768KB/384KB, L2-resident).
template<int IN_D, typename InT>
__global__ __launch_bounds__(256)
void conv_mfma_kernel(const InT* __restrict__ x, const unsigned short* __restrict__ wT,
                      const float* __restrict__ bias, const float* __restrict__ gamma,
                      const float* __restrict__ beta, unsigned short* __restrict__ out)
{
    constexpr int MT = 32;
    constexpr int KT = 3 * IN_D;
    constexpr int KSTEPS = KT / 32;

    __shared__ __align__(16) char xs_raw[(MT + 2) * IN_D * 2];
    __shared__ float red[MT][8];

    const int blocksPerBatch = T_ / MT;
    const int b  = blockIdx.x / blocksPerBatch;
    const int t0 = (blockIdx.x % blocksPerBatch) * MT;
    const int l  = threadIdx.x & 63;
    const int wv = threadIdx.x >> 6;

    // ---- stage rows t0-1 .. t0+MT into LDS as bf16, swizzled ----
    constexpr int CH = (MT + 2) * IN_D / 8;          // 16B-dest chunks (8 bf16)
    for (int c = threadIdx.x; c < CH; c += 256) {
        int j  = c / (IN_D / 8);
        int d8 = (c % (IN_D / 8)) * 8;
        int t  = t0 - 1 + j;
        uint4 pk = make_uint4(0u, 0u, 0u, 0u);
        if (t >= 0 && t < T_) {
            if constexpr (std::is_same_v<InT, float>) {
                const float4* src = reinterpret_cast<const float4*>(&x[((size_t)b * T_ + t) * IN_D + d8]);
                float4 a0 = src[0], a1 = src[1];
                pk.x = (unsigned)f2bf(a0.x) | ((unsigned)f2bf(a0.y) << 16);
                pk.y = (unsigned)f2bf(a0.z) | ((unsigned)f2bf(a0.w) << 16);
                pk.z = (unsigned)f2bf(a1.x) | ((unsigned)f2bf(a1.y) << 16);
                pk.w = (unsigned)f2bf(a1.z) | ((unsigned)f2bf(a1.w) << 16);
            } else {
                pk = *reinterpret_cast<const uint4*>(&x[((size_t)b * T_ + t) * IN_D + d8]);
            }
        }
        int byte = ((j * IN_D + d8) * 2) ^ ((j & 7) << 4);
        *reinterpret_cast<uint4*>(&xs_raw[byte]) = pk;
    }
    __syncthreads();

    // ---- MFMA K-loop ----
    f32x4 acc[2][4];
#pragma unroll
    for (int m = 0; m < 2; ++m)
#pragma unroll
        for (int n = 0; n < 4; ++n) acc[m][n] = (f32x4){0.f, 0.f, 0.f, 0.f};

    const int f_lane = wv * 64 + (l & 15);           // B-frag feature col (+n*16)
    const int k_lane = (l >> 4) * 8;                 // k-offset within a 32-chunk

#pragma unroll 4
    for (int ks = 0; ks < KSTEPS; ++ks) {
        int kk = ks * 32;
        int kp = kk / IN_D;                          // conv tap (0..2); 32 | IN_D so no straddle
        int dbase = (kk % IN_D) + k_lane;

        bf16x8 bfrag[4];
#pragma unroll
        for (int n = 0; n < 4; ++n)
            bfrag[n] = *reinterpret_cast<const bf16x8*>(
                &wT[(size_t)(f_lane + n * 16) * KT + kk + k_lane]);

        bf16x8 afrag[2];
#pragma unroll
        for (int m = 0; m < 2; ++m) {
            int j = m * 16 + (l & 15) + kp;          // input row for A row m*16+(l&15)
            int byte = ((j * IN_D + dbase) * 2) ^ ((j & 7) << 4);
            afrag[m] = *reinterpret_cast<const bf16x8*>(&xs_raw[byte]);
        }

#pragma unroll
        for (int m = 0; m < 2; ++m)
#pragma unroll
            for (int n = 0; n < 4; ++n)
                acc[m][n] = __builtin_amdgcn_mfma_f32_16x16x32_bf16(afrag[m], bfrag[n], acc[m][n], 0, 0, 0);
    }

    // ---- epilogue: bias, LN stats (16-lane shfl + cross-wave LDS), LN+ReLU, bf16 store ----
    float bv[4], gv[4], bev[4];
#pragma unroll
    for (int n = 0; n < 4; ++n) {
        int f = wv * 64 + n * 16 + (l & 15);
        bv[n] = bias[f]; gv[n] = gamma[f]; bev[n] = beta[f];
    }

#pragma unroll
    for (int m = 0; m < 2; ++m)
#pragma unroll
        for (int q = 0; q < 4; ++q) {
            float s = 0.f, s2 = 0.f;
#pragma unroll
            for (int n = 0; n < 4; ++n) {
                float v = acc[m][n][q] + bv[n];
                acc[m][n][q] = v;
                s += v; s2 += v * v;
            }
#pragma unroll
            for (int o = 1; o < 16; o <<= 1) { s += __shfl_xor(s, o); s2 += __shfl_xor(s2, o); }
            int row = m * 16 + (l >> 4) * 4 + q;     // C/D layout: col=l&15, row=(l>>4)*4+q
            if ((l & 15) == 0) { red[row][wv * 2] = s; red[row][wv * 2 + 1] = s2; }
        }
    __syncthreads();

#pragma unroll
    for (int m = 0; m < 2; ++m)
#pragma unroll
        for (int q = 0; q < 4; ++q) {
            int row = m * 16 + (l >> 4) * 4 + q;
            float s  = red[row][0] + red[row][2] + red[row][4] + red[row][6];
            float s2 = red[row][1] + red[row][3] + red[row][5] + red[row][7];
            float mu  = s * (1.f / F_);
            float var = s2 * (1.f / F_) - mu * mu;
            float rs  = rsqrtf(var + EPS_);
            size_t rbase = ((size_t)(b * T_ + t0 + row)) * F_;
#pragma unroll
            for (int n = 0; n < 4; ++n) {
                float y = (acc[m][n][q] - mu) * rs * gv[n] + bev[n];
                y = fmaxf(y, 0.f);
                out[rbase + wv * 64 + n * 16 + (l & 15)] = f2bf(y);
            }
        }
}

// dur_pred = relu(h2 @ wl + bl); one wave per (b,t) row; h2 is bf16.
__global__ __launch_bounds__(256)
void dur_kernel(const unsigned short* __restrict__ h2, const float* __restrict__ wl,
                const float* __restrict__ bl, float* __restrict__ dur)
{
    int lane = threadIdx.x & 63, wid = threadIdx.x >> 6;
    int row = blockIdx.x * 4 + wid;
    ushort4 hv = *reinterpret_cast<const ushort4*>(&h2[(size_t)row * F_ + lane * 4]);
    float4 wv = *reinterpret_cast<const float4*>(&wl[lane * 4]);
    float s = bf2f(hv.x) * wv.x + bf2f(hv.y) * wv.y + bf2f(hv.z) * wv.z + bf2f(hv.w) * wv.w;
#pragma unroll
    for (int o = 32; o; o >>= 1) s += __shfl_down(s, o);
    if (lane == 0) dur[row] = fmaxf(s + bl[0], 0.f);
}

__global__ void cumsum_kernel(const int* __restrict__ tgt, int* __restrict__ cum)
{
    int b = threadIdx.x;
    if (b >= B_) return;
    int run = 0;
    for (int t = 0; t < T_; ++t) { run += tgt[b * T_ + t]; cum[b * T_ + t] = run; }
}

__global__ __launch_bounds__(256)
void gather_kernel(const float* __restrict__ x, const int* __restrict__ cum,
                   float* __restrict__ out)
{
    int lane = threadIdx.x & 63, wid = threadIdx.x >> 6;
    int r = blockIdx.x * 4 + wid;
    int b   = r >> 12;
    int pos = r & (MEL - 1);
    const int* c = cum + b * T_;
    int total = c[T_ - 1];

    float4 v0 = make_float4(0.f, 0.f, 0.f, 0.f), v1 = v0;
    if (pos < total) {
        int lo = 0, hi = T_;
        while (lo < hi) { int mid = (lo + hi) >> 1; if (c[mid] <= pos) lo = mid + 1; else hi = mid; }
        int idx = min(lo, T_ - 1);
        const float* src = x + ((size_t)b * T_ + idx) * D_ + lane * 8;
        v0 = *reinterpret_cast<const float4*>(src);
        v1 = *reinterpret_cast<const float4*>(src + 4);
    }
    float* dst = out + (size_t)r * D_ + lane * 8;
    *reinterpret_cast<float4*>(dst)     = v0;
    *reinterpret_cast<float4*>(dst + 4) = v1;
}

extern "C" void kernel_launch(void* const* d_in, const int* in_sizes, int n_in,
                              void* d_out, int out_size, void* d_ws, size_t ws_size,
                              hipStream_t stream)
{
    const float* x      = (const float*)d_in[0];
    const int*   target = (const int*)d_in[1];
    const float* w1  = (const float*)d_in[3];
    const float* b1  = (const float*)d_in[4];
    const float* g1  = (const float*)d_in[5];
    const float* be1 = (const float*)d_in[6];
    const float* w2  = (const float*)d_in[7];
    const float* b2  = (const float*)d_in[8];
    const float* g2  = (const float*)d_in[9];
    const float* be2 = (const float*)d_in[10];
    const float* wl  = (const float*)d_in[11];
    const float* bl  = (const float*)d_in[12];

    float* out = (float*)d_out;                        // (B, MEL, D)
    float* dur = out + (size_t)B_ * MEL * D_;          // (B, T)

    char* ws = (char*)d_ws;
    unsigned short* w1T = (unsigned short*)ws;         ws += (size_t)F_ * (3 * D_) * 2;
    unsigned short* w2T = (unsigned short*)ws;         ws += (size_t)F_ * (3 * F_) * 2;
    unsigned short* h1  = (unsigned short*)ws;         ws += (size_t)B_ * T_ * F_ * 2;
    unsigned short* h2  = (unsigned short*)ws;         ws += (size_t)B_ * T_ * F_ * 2;
    int*            cum = (int*)ws;

    prep_w_kernel<<<(3 * D_ * F_ + 255) / 256, 256, 0, stream>>>(w1, w1T, 3 * D_);
    prep_w_kernel<<<(3 * F_ * F_ + 255) / 256, 256, 0, stream>>>(w2, w2T, 3 * F_);

    conv_mfma_kernel<D_, float><<<B_ * (T_ / 32), 256, 0, stream>>>(x, w1T, b1, g1, be1, h1);
    conv_mfma_kernel<F_, unsigned short><<<B_ * (T_ / 32), 256, 0, stream>>>(h1, w2T, b2, g2, be2, h2);

    dur_kernel<<<(B_ * T_) / 4, 256, 0, stream>>>(h2, wl, bl, dur);
    cumsum_kernel<<<1, 32, 0, stream>>>(target, cum);
    gather_kernel<<<(B_ * MEL) / 4, 256, 0, stream>>>(x, cum, out);
}

// Round 4
// 149.912 us; speedup vs baseline: 3.1109x; 1.1004x over previous
//
#include <hip/hip_runtime.h>
#include <type_traits>

#define B_   32
#define T_   512
#define D_   512
#define F_   256
#define MEL  4096
#define EPS_ 1e-5f

typedef __attribute__((ext_vector_type(8))) short bf16x8;
typedef __attribute__((ext_vector_type(4))) float f32x4;

__device__ inline unsigned short f2bf(float f) {
    unsigned u = __float_as_uint(f);
    unsigned r = (u + 0x7fff + ((u >> 16) & 1)) >> 16;   // RNE
    return (unsigned short)r;
}

// Transpose + convert weights: w[κ][f] f32 -> wT[f][κ] bf16.
__global__ void prep_w_kernel(const float* __restrict__ w, unsigned short* __restrict__ wT,
                              int KT)
{
    int idx = blockIdx.x * 256 + threadIdx.x;
    if (idx >= KT * F_) return;
    int kk = idx / F_;
    int f  = idx % F_;
    wT[(size_t)f * KT + kk] = f2bf(w[idx]);
}

// Fused conv1d(K=3,SAME) + bias + LayerNorm + ReLU via bf16 MFMA.
// MT=64 rows/block, 512 thr (8 waves = 2 rowgroups x 4 fgroups). Wave (rg,fg) computes
// rows [rg*32, rg*32+32) x f in [fg*64, fg*64+64) with acc[2][4].
// A (im2col) staged once in LDS bf16, XOR-swizzled; B streamed from L2 with a 3-buffer
// depth-2 prefetch pipeline. Optional fused dur_pred epilogue (conv2).
template<int IN_D, typename InT, bool FUSE_DUR>
__global__ __launch_bounds__(512)
void conv_mfma_kernel(const InT* __restrict__ x, const unsigned short* __restrict__ wT,
                      const float* __restrict__ bias, const float* __restrict__ gamma,
                      const float* __restrict__ beta, unsigned short* __restrict__ out,
                      const float* __restrict__ wl, const float* __restrict__ bl,
                      float* __restrict__ dur)
{
    constexpr int MT = 64;
    constexpr int KT = 3 * IN_D;
    constexpr int KSTEPS = KT / 32;          // 48 (conv1) / 24 (conv2), divisible by 3

    __shared__ __align__(16) char xs_raw[(MT + 2) * IN_D * 2];
    __shared__ float red[MT][8];
    __shared__ float redD[MT][4];

    const int blocksPerBatch = T_ / MT;      // 8
    const int b  = blockIdx.x / blocksPerBatch;
    const int t0 = (blockIdx.x % blocksPerBatch) * MT;
    const int l  = threadIdx.x & 63;
    const int wv = threadIdx.x >> 6;         // 0..7
    const int fg = wv & 3;                   // f-group
    const int rg = wv >> 2;                  // row-group

    // ---- stage rows t0-1 .. t0+MT into LDS as bf16, swizzled ----
    constexpr int CH = (MT + 2) * IN_D / 8;  // 16B-dest chunks
    for (int c = threadIdx.x; c < CH; c += 512) {
        int j  = c / (IN_D / 8);
        int d8 = (c % (IN_D / 8)) * 8;
        int t  = t0 - 1 + j;
        uint4 pk = make_uint4(0u, 0u, 0u, 0u);
        if (t >= 0 && t < T_) {
            if constexpr (std::is_same_v<InT, float>) {
                const float4* src = reinterpret_cast<const float4*>(&x[((size_t)b * T_ + t) * IN_D + d8]);
                float4 a0 = src[0], a1 = src[1];
                pk.x = (unsigned)f2bf(a0.x) | ((unsigned)f2bf(a0.y) << 16);
                pk.y = (unsigned)f2bf(a0.z) | ((unsigned)f2bf(a0.w) << 16);
                pk.z = (unsigned)f2bf(a1.x) | ((unsigned)f2bf(a1.y) << 16);
                pk.w = (unsigned)f2bf(a1.z) | ((unsigned)f2bf(a1.w) << 16);
            } else {
                pk = *reinterpret_cast<const uint4*>(&x[((size_t)b * T_ + t) * IN_D + d8]);
            }
        }
        int byte = ((j * IN_D + d8) * 2) ^ ((j & 7) << 4);
        *reinterpret_cast<uint4*>(&xs_raw[byte]) = pk;
    }
    __syncthreads();

    // ---- MFMA K-loop with depth-2 B prefetch ----
    f32x4 acc[2][4];
#pragma unroll
    for (int m = 0; m < 2; ++m)
#pragma unroll
        for (int n = 0; n < 4; ++n) acc[m][n] = (f32x4){0.f, 0.f, 0.f, 0.f};

    const int f_lane = fg * 64 + (l & 15);
    const int k_lane = (l >> 4) * 8;

    auto loadB = [&](bf16x8* dst, int ks) {
        int kse = ks < KSTEPS ? ks : KSTEPS - 1;      // clamp (prefetch tail)
        const unsigned short* p = &wT[(size_t)f_lane * KT + kse * 32 + k_lane];
#pragma unroll
        for (int n = 0; n < 4; ++n)
            dst[n] = *reinterpret_cast<const bf16x8*>(p + (size_t)n * 16 * KT);
    };
    auto loadA = [&](bf16x8* dst, int ks) {
        int kk = ks * 32;
        int kp = kk / IN_D;                           // conv tap 0..2
        int dbase = (kk % IN_D) + k_lane;
#pragma unroll
        for (int m = 0; m < 2; ++m) {
            int j = rg * 32 + m * 16 + (l & 15) + kp;
            int byte = ((j * IN_D + dbase) * 2) ^ ((j & 7) << 4);
            dst[m] = *reinterpret_cast<const bf16x8*>(&xs_raw[byte]);
        }
    };
    auto mfma8 = [&](bf16x8* A, bf16x8* Bv) {
#pragma unroll
        for (int m = 0; m < 2; ++m)
#pragma unroll
            for (int n = 0; n < 4; ++n)
                acc[m][n] = __builtin_amdgcn_mfma_f32_16x16x32_bf16(A[m], Bv[n], acc[m][n], 0, 0, 0);
    };

    bf16x8 B0[4], B1[4], B2[4], A[2];
    loadB(B0, 0);
    loadB(B1, 1);
#pragma unroll
    for (int ks = 0; ks < KSTEPS; ks += 3) {
        loadB(B2, ks + 2);
        loadA(A, ks);
        mfma8(A, B0);
        loadB(B0, ks + 3);
        loadA(A, ks + 1);
        mfma8(A, B1);
        loadB(B1, ks + 4);
        loadA(A, ks + 2);
        mfma8(A, B2);
    }

    // ---- epilogue: bias, LN stats, LN+ReLU store, optional fused dur ----
    float bv[4], gv[4], bev[4], wlv[4];
#pragma unroll
    for (int n = 0; n < 4; ++n) {
        int f = fg * 64 + n * 16 + (l & 15);
        bv[n] = bias[f]; gv[n] = gamma[f]; bev[n] = beta[f];
        if constexpr (FUSE_DUR) wlv[n] = wl[f];
    }

#pragma unroll
    for (int m = 0; m < 2; ++m)
#pragma unroll
        for (int q = 0; q < 4; ++q) {
            float s = 0.f, s2 = 0.f;
#pragma unroll
            for (int n = 0; n < 4; ++n) {
                float v = acc[m][n][q] + bv[n];
                acc[m][n][q] = v;
                s += v; s2 += v * v;
            }
#pragma unroll
            for (int o = 1; o < 16; o <<= 1) { s += __shfl_xor(s, o); s2 += __shfl_xor(s2, o); }
            int row = rg * 32 + m * 16 + (l >> 4) * 4 + q;   // C/D: col=l&15, row=(l>>4)*4+q
            if ((l & 15) == 0) { red[row][fg * 2] = s; red[row][fg * 2 + 1] = s2; }
        }
    __syncthreads();

#pragma unroll
    for (int m = 0; m < 2; ++m)
#pragma unroll
        for (int q = 0; q < 4; ++q) {
            int row = rg * 32 + m * 16 + (l >> 4) * 4 + q;
            float s  = red[row][0] + red[row][2] + red[row][4] + red[row][6];
            float s2 = red[row][1] + red[row][3] + red[row][5] + red[row][7];
            float mu  = s * (1.f / F_);
            float var = s2 * (1.f / F_) - mu * mu;
            float rs  = rsqrtf(var + EPS_);
            size_t rbase = ((size_t)(b * T_ + t0 + row)) * F_;
            float part = 0.f;
#pragma unroll
            for (int n = 0; n < 4; ++n) {
                float y = (acc[m][n][q] - mu) * rs * gv[n] + bev[n];
                y = fmaxf(y, 0.f);
                out[rbase + fg * 64 + n * 16 + (l & 15)] = f2bf(y);
                if constexpr (FUSE_DUR) part = fmaf(y, wlv[n], part);
            }
            if constexpr (FUSE_DUR) {
#pragma unroll
                for (int o = 1; o < 16; o <<= 1) part += __shfl_xor(part, o);
                if ((l & 15) == 0) redD[row][fg] = part;
            }
        }

    if constexpr (FUSE_DUR) {
        __syncthreads();
        if (threadIdx.x < MT) {
            float s = redD[threadIdx.x][0] + redD[threadIdx.x][1]
                    + redD[threadIdx.x][2] + redD[threadIdx.x][3] + bl[0];
            dur[(size_t)b * T_ + t0 + threadIdx.x] = fmaxf(s, 0.f);
        }
    }
}

// Per-batch inclusive cumsum of target via block scan: grid=B_, block=256 (2 elems/thread).
__global__ __launch_bounds__(256)
void cumsum_kernel(const int* __restrict__ tgt, int* __restrict__ cum)
{
    int b = blockIdx.x;
    int tid = threadIdx.x;
    int t0 = tid * 2;
    int a0 = tgt[b * T_ + t0], a1 = tgt[b * T_ + t0 + 1];
    int lane = tid & 63, w = tid >> 6;
    int v = a0 + a1;
#pragma unroll
    for (int o = 1; o < 64; o <<= 1) { int u = __shfl_up(v, o); if (lane >= o) v += u; }
    __shared__ int wsum[4];
    if (lane == 63) wsum[w] = v;
    __syncthreads();
    int base = 0;
#pragma unroll
    for (int i = 0; i < 4; ++i) if (i < w) base += wsum[i];
    int incl = base + v;                      // inclusive sum over pairs
    cum[b * T_ + t0]     = incl - a1;
    cum[b * T_ + t0 + 1] = incl;
}

// Length-regulator gather: one wave per output (b,pos) row; binary search cum.
__global__ __launch_bounds__(256)
void gather_kernel(const float* __restrict__ x, const int* __restrict__ cum,
                   float* __restrict__ out)
{
    int lane = threadIdx.x & 63, wid = threadIdx.x >> 6;
    int r = blockIdx.x * 4 + wid;
    int b   = r >> 12;                        // / MEL
    int pos = r & (MEL - 1);
    const int* c = cum + b * T_;
    int total = c[T_ - 1];

    float4 v0 = make_float4(0.f, 0.f, 0.f, 0.f), v1 = v0;
    if (pos < total) {
        int lo = 0, hi = T_;
        while (lo < hi) { int mid = (lo + hi) >> 1; if (c[mid] <= pos) lo = mid + 1; else hi = mid; }
        int idx = min(lo, T_ - 1);
        const float* src = x + ((size_t)b * T_ + idx) * D_ + lane * 8;
        v0 = *reinterpret_cast<const float4*>(src);
        v1 = *reinterpret_cast<const float4*>(src + 4);
    }
    float* dst = out + (size_t)r * D_ + lane * 8;
    *reinterpret_cast<float4*>(dst)     = v0;
    *reinterpret_cast<float4*>(dst + 4) = v1;
}

extern "C" void kernel_launch(void* const* d_in, const int* in_sizes, int n_in,
                              void* d_out, int out_size, void* d_ws, size_t ws_size,
                              hipStream_t stream)
{
    const float* x      = (const float*)d_in[0];
    const int*   target = (const int*)d_in[1];
    const float* w1  = (const float*)d_in[3];
    const float* b1  = (const float*)d_in[4];
    const float* g1  = (const float*)d_in[5];
    const float* be1 = (const float*)d_in[6];
    const float* w2  = (const float*)d_in[7];
    const float* b2  = (const float*)d_in[8];
    const float* g2  = (const float*)d_in[9];
    const float* be2 = (const float*)d_in[10];
    const float* wl  = (const float*)d_in[11];
    const float* bl  = (const float*)d_in[12];

    float* out = (float*)d_out;                        // (B, MEL, D)
    float* dur = out + (size_t)B_ * MEL * D_;          // (B, T)

    char* ws = (char*)d_ws;
    unsigned short* w1T = (unsigned short*)ws;         ws += (size_t)F_ * (3 * D_) * 2;
    unsigned short* w2T = (unsigned short*)ws;         ws += (size_t)F_ * (3 * F_) * 2;
    unsigned short* h1  = (unsigned short*)ws;         ws += (size_t)B_ * T_ * F_ * 2;
    unsigned short* h2  = (unsigned short*)ws;         ws += (size_t)B_ * T_ * F_ * 2;
    int*            cum = (int*)ws;

    prep_w_kernel<<<(3 * D_ * F_ + 255) / 256, 256, 0, stream>>>(w1, w1T, 3 * D_);
    prep_w_kernel<<<(3 * F_ * F_ + 255) / 256, 256, 0, stream>>>(w2, w2T, 3 * F_);

    conv_mfma_kernel<D_, float, false><<<B_ * (T_ / 64), 512, 0, stream>>>(
        x, w1T, b1, g1, be1, h1, nullptr, nullptr, nullptr);
    conv_mfma_kernel<F_, unsigned short, true><<<B_ * (T_ / 64), 512, 0, stream>>>(
        h1, w2T, b2, g2, be2, h2, wl, bl, dur);

    cumsum_kernel<<<B_, 256, 0, stream>>>(target, cum);
    gather_kernel<<<(B_ * MEL) / 4, 256, 0, stream>>>(x, cum, out);
}

// Round 5
// 112.996 us; speedup vs baseline: 4.1272x; 1.3267x over previous
//
#include <hip/hip_runtime.h>
#include <type_traits>

#define B_   32
#define T_   512
#define D_   512
#define F_   256
#define MEL  4096
#define EPS_ 1e-5f

typedef __attribute__((ext_vector_type(8))) short bf16x8;
typedef __attribute__((ext_vector_type(4))) float f32x4;

#define GLL16(gp, lp) \
    __builtin_amdgcn_global_load_lds((const __attribute__((address_space(1))) void*)(gp), \
                                     (__attribute__((address_space(3))) void*)(lp), 16, 0, 0)
#define BARRIER() do { asm volatile("" ::: "memory"); __builtin_amdgcn_s_barrier(); \
                       asm volatile("" ::: "memory"); } while (0)

__device__ inline unsigned short f2bf(float f) {
    unsigned u = __float_as_uint(f);
    unsigned r = (u + 0x7fff + ((u >> 16) & 1)) >> 16;   // RNE
    return (unsigned short)r;
}

// Transpose + convert both weight tensors: w[κ][f] f32 -> wT[f][κ] bf16.
__global__ void prep_w_kernel(const float* __restrict__ w1, const float* __restrict__ w2,
                              unsigned short* __restrict__ w1T, unsigned short* __restrict__ w2T)
{
    int idx = blockIdx.x * 256 + threadIdx.x;
    if (idx < 3 * D_ * F_) {
        int kk = idx / F_, f = idx % F_;
        w1T[(size_t)f * (3 * D_) + kk] = f2bf(w1[idx]);
    } else {
        int j = idx - 3 * D_ * F_;
        if (j < 3 * F_ * F_) {
            int kk = j / F_, f = j % F_;
            w2T[(size_t)f * (3 * F_) + kk] = f2bf(w2[j]);
        }
    }
}

// Fused conv1d(K=3,SAME) + bias + LayerNorm + ReLU via bf16 MFMA.
// MT=64 rows/block, 512 thr (8 waves = 2 rowgroups x 4 fgroups), acc[2][4] per wave.
// A (im2col) staged once in LDS (XOR-swizzled). B staged through LDS via global_load_lds,
// double-buffered at 64-k granularity with counted vmcnt(4) — loads stay in flight across
// barriers (T3/T4). B LDS layout [f][64k] with XOR swizzle via pre-swizzled global source.
template<int IN_D, typename InT, bool FUSE_DUR>
__global__ __launch_bounds__(512, 1)
void conv_mfma_kernel(const InT* __restrict__ x, const unsigned short* __restrict__ wT,
                      const float* __restrict__ bias, const float* __restrict__ gamma,
                      const float* __restrict__ beta, unsigned short* __restrict__ out,
                      const float* __restrict__ wl, const float* __restrict__ bl,
                      float* __restrict__ dur)
{
    constexpr int MT = 64;
    constexpr int KT = 3 * IN_D;
    constexpr int PHASES = KT / 64;          // 24 (conv1) / 12 (conv2)

    __shared__ __align__(16) char xs_raw[(MT + 2) * IN_D * 2];
    __shared__ __align__(16) unsigned short xsB[2 * 16384];   // 2 x 32 KB B buffers
    __shared__ float red[MT][8];
    __shared__ float redD[MT][4];

    const int blocksPerBatch = T_ / MT;      // 8
    const int b  = blockIdx.x / blocksPerBatch;
    const int t0 = (blockIdx.x % blocksPerBatch) * MT;
    const int l  = threadIdx.x & 63;
    const int wv = threadIdx.x >> 6;         // 0..7
    const int fg = wv & 3;                   // f-group
    const int rg = wv >> 2;                  // row-group

    // ---- stage A rows t0-1 .. t0+MT into LDS as bf16, swizzled ----
    constexpr int CH = (MT + 2) * IN_D / 8;
    for (int c = threadIdx.x; c < CH; c += 512) {
        int j  = c / (IN_D / 8);
        int d8 = (c % (IN_D / 8)) * 8;
        int t  = t0 - 1 + j;
        uint4 pk = make_uint4(0u, 0u, 0u, 0u);
        if (t >= 0 && t < T_) {
            if constexpr (std::is_same_v<InT, float>) {
                const float4* src = reinterpret_cast<const float4*>(&x[((size_t)b * T_ + t) * IN_D + d8]);
                float4 a0 = src[0], a1 = src[1];
                pk.x = (unsigned)f2bf(a0.x) | ((unsigned)f2bf(a0.y) << 16);
                pk.y = (unsigned)f2bf(a0.z) | ((unsigned)f2bf(a0.w) << 16);
                pk.z = (unsigned)f2bf(a1.x) | ((unsigned)f2bf(a1.y) << 16);
                pk.w = (unsigned)f2bf(a1.z) | ((unsigned)f2bf(a1.w) << 16);
            } else {
                pk = *reinterpret_cast<const uint4*>(&x[((size_t)b * T_ + t) * IN_D + d8]);
            }
        }
        int byte = ((j * IN_D + d8) * 2) ^ ((j & 7) << 4);
        *reinterpret_cast<uint4*>(&xs_raw[byte]) = pk;
    }

    // ---- epilogue scalars (loaded before the fence so they don't pollute vmcnt) ----
    float bv[4], gv[4], bev[4], wlv[4];
#pragma unroll
    for (int n = 0; n < 4; ++n) {
        int f = fg * 64 + n * 16 + (l & 15);
        bv[n] = bias[f]; gv[n] = gamma[f]; bev[n] = beta[f];
        if constexpr (FUSE_DUR) wlv[n] = wl[f];
    }
    float blv = FUSE_DUR ? bl[0] : 0.f;

    __syncthreads();   // drains everything: A-LDS writes + scalar loads complete

    // ---- B staging machinery ----
    // Buffer layout: [256 f][8 kg][8 k] bf16 with slot XOR: chunk(f,kg) at shorts
    // f*64 + (kg^(f&7))*8. gll dest is lane-linear; XOR applied on global source.
    const int sbase = wv * 4;
    auto stageB = [&](int ph, int buf) {
        int p = ph < PHASES ? ph : PHASES - 1;          // clamp: redundant, harmless
        unsigned short* lb = &xsB[buf * 16384];
#pragma unroll
        for (int i = 0; i < 4; ++i) {
            int s = sbase + i;                          // 0..31, wave-uniform
            int c = s * 64 + l;                         // 16B-chunk index
            int f = c >> 3;
            int kg = (c & 7) ^ (f & 7);                 // inverse swizzle on source
            const unsigned short* src = wT + (size_t)f * KT + p * 64 + kg * 8;
            GLL16(src, lb + s * 512);
        }
    };

    auto loadBfrag = [&](bf16x8* dst, int buf, int kk2) {
#pragma unroll
        for (int n = 0; n < 4; ++n) {
            int f  = fg * 64 + n * 16 + (l & 15);
            int kg = kk2 * 4 + (l >> 4);
            dst[n] = *reinterpret_cast<const bf16x8*>(&xsB[buf * 16384 + f * 64 + ((kg ^ (f & 7)) * 8)]);
        }
    };
    const int k_lane = (l >> 4) * 8;
    auto loadA = [&](bf16x8* dst, int kk) {
        int kp = kk / IN_D;                             // conv tap 0..2
        int dbase = (kk % IN_D) + k_lane;
#pragma unroll
        for (int m = 0; m < 2; ++m) {
            int j = rg * 32 + m * 16 + (l & 15) + kp;
            int byte = ((j * IN_D + dbase) * 2) ^ ((j & 7) << 4);
            dst[m] = *reinterpret_cast<const bf16x8*>(&xs_raw[byte]);
        }
    };

    f32x4 acc[2][4];
#pragma unroll
    for (int m = 0; m < 2; ++m)
#pragma unroll
        for (int n = 0; n < 4; ++n) acc[m][n] = (f32x4){0.f, 0.f, 0.f, 0.f};

    // ---- pipelined K-loop: 2 phases in flight, wait for oldest only ----
    stageB(0, 0);
    stageB(1, 1);
    for (int p = 0; p < PHASES; ++p) {
        asm volatile("s_waitcnt vmcnt(4)" ::: "memory");   // oldest phase's 4 gll done
        BARRIER();
        int buf = p & 1;
#pragma unroll
        for (int kk2 = 0; kk2 < 2; ++kk2) {
            int kk = p * 64 + kk2 * 32;
            bf16x8 Bv[4], Av[2];
            loadBfrag(Bv, buf, kk2);
            loadA(Av, kk);
#pragma unroll
            for (int m = 0; m < 2; ++m)
#pragma unroll
                for (int n = 0; n < 4; ++n)
                    acc[m][n] = __builtin_amdgcn_mfma_f32_16x16x32_bf16(Av[m], Bv[n], acc[m][n], 0, 0, 0);
        }
        BARRIER();                                  // all waves done reading buf
        stageB(p + 2, buf);                         // overwrite it for phase p+2
    }

    // ---- epilogue: bias, LN stats, LN+ReLU store, optional fused dur ----
#pragma unroll
    for (int m = 0; m < 2; ++m)
#pragma unroll
        for (int q = 0; q < 4; ++q) {
            float s = 0.f, s2 = 0.f;
#pragma unroll
            for (int n = 0; n < 4; ++n) {
                float v = acc[m][n][q] + bv[n];
                acc[m][n][q] = v;
                s += v; s2 += v * v;
            }
#pragma unroll
            for (int o = 1; o < 16; o <<= 1) { s += __shfl_xor(s, o); s2 += __shfl_xor(s2, o); }
            int row = rg * 32 + m * 16 + (l >> 4) * 4 + q;   // C/D: col=l&15, row=(l>>4)*4+q
            if ((l & 15) == 0) { red[row][fg * 2] = s; red[row][fg * 2 + 1] = s2; }
        }
    __syncthreads();

#pragma unroll
    for (int m = 0; m < 2; ++m)
#pragma unroll
        for (int q = 0; q < 4; ++q) {
            int row = rg * 32 + m * 16 + (l >> 4) * 4 + q;
            float s  = red[row][0] + red[row][2] + red[row][4] + red[row][6];
            float s2 = red[row][1] + red[row][3] + red[row][5] + red[row][7];
            float mu  = s * (1.f / F_);
            float var = s2 * (1.f / F_) - mu * mu;
            float rs  = rsqrtf(var + EPS_);
            size_t rbase = ((size_t)(b * T_ + t0 + row)) * F_;
            float part = 0.f;
#pragma unroll
            for (int n = 0; n < 4; ++n) {
                float y = (acc[m][n][q] - mu) * rs * gv[n] + bev[n];
                y = fmaxf(y, 0.f);
                out[rbase + fg * 64 + n * 16 + (l & 15)] = f2bf(y);
                if constexpr (FUSE_DUR) part = fmaf(y, wlv[n], part);
            }
            if constexpr (FUSE_DUR) {
#pragma unroll
                for (int o = 1; o < 16; o <<= 1) part += __shfl_xor(part, o);
                if ((l & 15) == 0) redD[row][fg] = part;
            }
        }

    if constexpr (FUSE_DUR) {
        __syncthreads();
        if (threadIdx.x < MT) {
            float s = redD[threadIdx.x][0] + redD[threadIdx.x][1]
                    + redD[threadIdx.x][2] + redD[threadIdx.x][3] + blv;
            dur[(size_t)b * T_ + t0 + threadIdx.x] = fmaxf(s, 0.f);
        }
    }
}

// Per-batch inclusive cumsum of target via block scan: grid=B_, block=256 (2 elems/thread).
__global__ __launch_bounds__(256)
void cumsum_kernel(const int* __restrict__ tgt, int* __restrict__ cum)
{
    int b = blockIdx.x;
    int tid = threadIdx.x;
    int t0 = tid * 2;
    int a0 = tgt[b * T_ + t0], a1 = tgt[b * T_ + t0 + 1];
    int lane = tid & 63, w = tid >> 6;
    int v = a0 + a1;
#pragma unroll
    for (int o = 1; o < 64; o <<= 1) { int u = __shfl_up(v, o); if (lane >= o) v += u; }
    __shared__ int wsum[4];
    if (lane == 63) wsum[w] = v;
    __syncthreads();
    int base = 0;
#pragma unroll
    for (int i = 0; i < 4; ++i) if (i < w) base += wsum[i];
    int incl = base + v;
    cum[b * T_ + t0]     = incl - a1;
    cum[b * T_ + t0 + 1] = incl;
}

// Length-regulator gather: one wave per output (b,pos) row; binary search cum.
__global__ __launch_bounds__(256)
void gather_kernel(const float* __restrict__ x, const int* __restrict__ cum,
                   float* __restrict__ out)
{
    int lane = threadIdx.x & 63, wid = threadIdx.x >> 6;
    int r = blockIdx.x * 4 + wid;
    int b   = r >> 12;                        // / MEL
    int pos = r & (MEL - 1);
    const int* c = cum + b * T_;
    int total = c[T_ - 1];

    float4 v0 = make_float4(0.f, 0.f, 0.f, 0.f), v1 = v0;
    if (pos < total) {
        int lo = 0, hi = T_;
        while (lo < hi) { int mid = (lo + hi) >> 1; if (c[mid] <= pos) lo = mid + 1; else hi = mid; }
        int idx = min(lo, T_ - 1);
        const float* src = x + ((size_t)b * T_ + idx) * D_ + lane * 8;
        v0 = *reinterpret_cast<const float4*>(src);
        v1 = *reinterpret_cast<const float4*>(src + 4);
    }
    float* dst = out + (size_t)r * D_ + lane * 8;
    *reinterpret_cast<float4*>(dst)     = v0;
    *reinterpret_cast<float4*>(dst + 4) = v1;
}

extern "C" void kernel_launch(void* const* d_in, const int* in_sizes, int n_in,
                              void* d_out, int out_size, void* d_ws, size_t ws_size,
                              hipStream_t stream)
{
    const float* x      = (const float*)d_in[0];
    const int*   target = (const int*)d_in[1];
    const float* w1  = (const float*)d_in[3];
    const float* b1  = (const float*)d_in[4];
    const float* g1  = (const float*)d_in[5];
    const float* be1 = (const float*)d_in[6];
    const float* w2  = (const float*)d_in[7];
    const float* b2  = (const float*)d_in[8];
    const float* g2  = (const float*)d_in[9];
    const float* be2 = (const float*)d_in[10];
    const float* wl  = (const float*)d_in[11];
    const float* bl  = (const float*)d_in[12];

    float* out = (float*)d_out;                        // (B, MEL, D)
    float* dur = out + (size_t)B_ * MEL * D_;          // (B, T)

    char* ws = (char*)d_ws;
    unsigned short* w1T = (unsigned short*)ws;         ws += (size_t)F_ * (3 * D_) * 2;
    unsigned short* w2T = (unsigned short*)ws;         ws += (size_t)F_ * (3 * F_) * 2;
    unsigned short* h1  = (unsigned short*)ws;         ws += (size_t)B_ * T_ * F_ * 2;
    unsigned short* h2  = (unsigned short*)ws;         ws += (size_t)B_ * T_ * F_ * 2;
    int*            cum = (int*)ws;

    const int prepN = 3 * D_ * F_ + 3 * F_ * F_;
    prep_w_kernel<<<(prepN + 255) / 256, 256, 0, stream>>>(w1, w2, w1T, w2T);

    conv_mfma_kernel<D_, float, false><<<B_ * (T_ / 64), 512, 0, stream>>>(
        x, w1T, b1, g1, be1, h1, nullptr, nullptr, nullptr);
    conv_mfma_kernel<F_, unsigned short, true><<<B_ * (T_ / 64), 512, 0, stream>>>(
        h1, w2T, b2, g2, be2, h2, wl, bl, dur);

    cumsum_kernel<<<B_, 256, 0, stream>>>(target, cum);
    gather_kernel<<<(B_ * MEL) / 4, 256, 0, stream>>>(x, cum, out);
}

// Round 6
// 108.580 us; speedup vs baseline: 4.2950x; 1.0407x over previous
//
#include <hip/hip_runtime.h>
#include <type_traits>

#define B_   32
#define T_   512
#define D_   512
#define F_   256
#define MEL  4096
#define EPS_ 1e-5f

typedef __attribute__((ext_vector_type(8))) short bf16x8;
typedef __attribute__((ext_vector_type(4))) float f32x4;

#define GLL16(gp, lp) \
    __builtin_amdgcn_global_load_lds((const __attribute__((address_space(1))) void*)(gp), \
                                     (__attribute__((address_space(3))) void*)(lp), 16, 0, 0)
#define BARRIER() do { asm volatile("" ::: "memory"); __builtin_amdgcn_s_barrier(); \
                       asm volatile("" ::: "memory"); } while (0)

__device__ inline unsigned short f2bf(float f) {
    unsigned u = __float_as_uint(f);
    unsigned r = (u + 0x7fff + ((u >> 16) & 1)) >> 16;   // RNE
    return (unsigned short)r;
}

// ---------------------------------------------------------------------------
// prep: weight transpose/convert (blocks 0..2303) + per-batch cumsum & idx
// precompute (blocks 2304..2335). idx[b][pos] = source row, or -1 (masked).
// ---------------------------------------------------------------------------
#define PREP_WBLOCKS 2304   // (3*D_*F_ + 3*F_*F_) / 256

__global__ __launch_bounds__(256)
void prep_kernel(const float* __restrict__ w1, const float* __restrict__ w2,
                 const int* __restrict__ tgt,
                 unsigned short* __restrict__ w1T, unsigned short* __restrict__ w2T,
                 int* __restrict__ gidx)
{
    __shared__ int lcum[T_];
    __shared__ int wsum[4];

    int bid = blockIdx.x;
    int tid = threadIdx.x;
    if (bid < PREP_WBLOCKS) {
        int idx = bid * 256 + tid;
        if (idx < 3 * D_ * F_) {
            int kk = idx / F_, f = idx % F_;
            w1T[(size_t)f * (3 * D_) + kk] = f2bf(w1[idx]);
        } else {
            int j = idx - 3 * D_ * F_;
            int kk = j / F_, f = j % F_;
            w2T[(size_t)f * (3 * F_) + kk] = f2bf(w2[j]);
        }
        return;
    }

    // ---- scan + idx block for batch b ----
    int b = bid - PREP_WBLOCKS;
    int t0 = tid * 2;
    int a0 = tgt[b * T_ + t0], a1 = tgt[b * T_ + t0 + 1];
    int lane = tid & 63, w = tid >> 6;
    int v = a0 + a1;
#pragma unroll
    for (int o = 1; o < 64; o <<= 1) { int u = __shfl_up(v, o); if (lane >= o) v += u; }
    if (lane == 63) wsum[w] = v;
    __syncthreads();
    int base = 0;
#pragma unroll
    for (int i = 0; i < 4; ++i) if (i < w) base += wsum[i];
    int incl = base + v;
    lcum[t0]     = incl - a1;
    lcum[t0 + 1] = incl;
    __syncthreads();

    int total = lcum[T_ - 1];
#pragma unroll
    for (int k = 0; k < MEL / 256; ++k) {
        int pos = tid + k * 256;
        int lo = 0, hi = T_;
        while (lo < hi) { int mid = (lo + hi) >> 1; if (lcum[mid] <= pos) lo = mid + 1; else hi = mid; }
        gidx[b * MEL + pos] = (pos < total) ? min(lo, T_ - 1) : -1;
    }
}

// ---------------------------------------------------------------------------
// Fused conv1d(K=3,SAME)+bias+LN+ReLU (waves 0-7) co-scheduled with the
// length-regulator gather copy (waves 8-15). 1024 threads, 1 block/CU.
// Conv: MT=64 rows x 256 f, A im2col in LDS (XOR-swizzled), B double-buffered
// through LDS via global_load_lds with counted vmcnt(4) (T3/T4).
// Gather waves execute the conv path's exact s_barrier count as pacing.
// ---------------------------------------------------------------------------
template<int IN_D, typename InT, bool FUSE_DUR, int GROWS, int GOFF>
__global__ __launch_bounds__(1024)
void conv_gather_kernel(const InT* __restrict__ x, const unsigned short* __restrict__ wT,
                        const float* __restrict__ bias, const float* __restrict__ gamma,
                        const float* __restrict__ beta, unsigned short* __restrict__ out,
                        const float* __restrict__ wl, const float* __restrict__ bl,
                        float* __restrict__ dur,
                        const float* __restrict__ xf, const int* __restrict__ gidx,
                        float* __restrict__ gout)
{
    constexpr int MT = 64;
    constexpr int KT = 3 * IN_D;
    constexpr int PHASES = KT / 64;                      // 24 (conv1) / 12 (conv2)
    constexpr int NBAR = 2 + 2 * PHASES + (FUSE_DUR ? 1 : 0);

    __shared__ __align__(16) char xs_raw[(MT + 2) * IN_D * 2];
    __shared__ __align__(16) unsigned short xsB[2 * 16384];   // 2 x 32 KB B buffers
    __shared__ float red[MT][8];
    __shared__ float redD[MT][4];

    const int l = threadIdx.x & 63;

    if (threadIdx.x >= 512) {
        // ================= gather waves =================
        const int gw = (threadIdx.x >> 6) - 8;           // 0..7
        const int rbase = GOFF + blockIdx.x * (GROWS * 8) + gw * GROWS;
        int myidx = (l < GROWS) ? gidx[rbase + l] : -1;
        int done = 0;
        for (int bar = 0; bar < NBAR; ++bar) {
            __builtin_amdgcn_s_barrier();
            int tgt = (int)(((long)(bar + 1) * GROWS) / NBAR);
            for (; done < tgt; ++done) {
                int r = rbase + done;
                int ix = __shfl(myidx, done);            // uniform across wave
                float4 v0 = make_float4(0.f, 0.f, 0.f, 0.f), v1 = v0;
                if (ix >= 0) {
                    const float* s = xf + ((size_t)(r >> 12) * T_ + ix) * D_ + l * 8;
                    v0 = *reinterpret_cast<const float4*>(s);
                    v1 = *reinterpret_cast<const float4*>(s + 4);
                }
                float* d = gout + (size_t)r * D_ + l * 8;
                *reinterpret_cast<float4*>(d)     = v0;
                *reinterpret_cast<float4*>(d + 4) = v1;
            }
        }
        return;
    }

    // ================= conv waves (threads 0..511) =================
    const int blocksPerBatch = T_ / MT;                  // 8
    const int b  = blockIdx.x / blocksPerBatch;
    const int t0 = (blockIdx.x % blocksPerBatch) * MT;
    const int wv = threadIdx.x >> 6;                     // 0..7
    const int fg = wv & 3;
    const int rg = wv >> 2;

    // ---- stage A rows t0-1 .. t0+MT into LDS as bf16, swizzled ----
    constexpr int CH = (MT + 2) * IN_D / 8;
    for (int c = threadIdx.x; c < CH; c += 512) {
        int j  = c / (IN_D / 8);
        int d8 = (c % (IN_D / 8)) * 8;
        int t  = t0 - 1 + j;
        uint4 pk = make_uint4(0u, 0u, 0u, 0u);
        if (t >= 0 && t < T_) {
            if constexpr (std::is_same_v<InT, float>) {
                const float4* src = reinterpret_cast<const float4*>(&x[((size_t)b * T_ + t) * IN_D + d8]);
                float4 a0 = src[0], a1 = src[1];
                pk.x = (unsigned)f2bf(a0.x) | ((unsigned)f2bf(a0.y) << 16);
                pk.y = (unsigned)f2bf(a0.z) | ((unsigned)f2bf(a0.w) << 16);
                pk.z = (unsigned)f2bf(a1.x) | ((unsigned)f2bf(a1.y) << 16);
                pk.w = (unsigned)f2bf(a1.z) | ((unsigned)f2bf(a1.w) << 16);
            } else {
                pk = *reinterpret_cast<const uint4*>(&x[((size_t)b * T_ + t) * IN_D + d8]);
            }
        }
        int byte = ((j * IN_D + d8) * 2) ^ ((j & 7) << 4);
        *reinterpret_cast<uint4*>(&xs_raw[byte]) = pk;
    }

    float bv[4], gv[4], bev[4], wlv[4];
#pragma unroll
    for (int n = 0; n < 4; ++n) {
        int f = fg * 64 + n * 16 + (l & 15);
        bv[n] = bias[f]; gv[n] = gamma[f]; bev[n] = beta[f];
        if constexpr (FUSE_DUR) wlv[n] = wl[f];
    }
    float blv = FUSE_DUR ? bl[0] : 0.f;

    __syncthreads();                                     // barrier #1

    // ---- B staging: [256 f][8 kg][8 k], slot XOR kg^(f&7); gll dest linear ----
    const int sbase = wv * 4;
    auto stageB = [&](int ph, int buf) {
        int p = ph < PHASES ? ph : PHASES - 1;
        unsigned short* lb = &xsB[buf * 16384];
#pragma unroll
        for (int i = 0; i < 4; ++i) {
            int s = sbase + i;
            int c = s * 64 + l;
            int f = c >> 3;
            int kg = (c & 7) ^ (f & 7);
            const unsigned short* src = wT + (size_t)f * KT + p * 64 + kg * 8;
            GLL16(src, lb + s * 512);
        }
    };
    auto loadBfrag = [&](bf16x8* dst, int buf, int kk2) {
#pragma unroll
        for (int n = 0; n < 4; ++n) {
            int f  = fg * 64 + n * 16 + (l & 15);
            int kg = kk2 * 4 + (l >> 4);
            dst[n] = *reinterpret_cast<const bf16x8*>(&xsB[buf * 16384 + f * 64 + ((kg ^ (f & 7)) * 8)]);
        }
    };
    const int k_lane = (l >> 4) * 8;
    auto loadA = [&](bf16x8* dst, int kk) {
        int kp = kk / IN_D;
        int dbase = (kk % IN_D) + k_lane;
#pragma unroll
        for (int m = 0; m < 2; ++m) {
            int j = rg * 32 + m * 16 + (l & 15) + kp;
            int byte = ((j * IN_D + dbase) * 2) ^ ((j & 7) << 4);
            dst[m] = *reinterpret_cast<const bf16x8*>(&xs_raw[byte]);
        }
    };

    f32x4 acc[2][4];
#pragma unroll
    for (int m = 0; m < 2; ++m)
#pragma unroll
        for (int n = 0; n < 4; ++n) acc[m][n] = (f32x4){0.f, 0.f, 0.f, 0.f};

    stageB(0, 0);
    stageB(1, 1);
    for (int p = 0; p < PHASES; ++p) {
        asm volatile("s_waitcnt vmcnt(4)" ::: "memory");
        BARRIER();                                       // 2 per phase
        int buf = p & 1;
#pragma unroll
        for (int kk2 = 0; kk2 < 2; ++kk2) {
            int kk = p * 64 + kk2 * 32;
            bf16x8 Bv[4], Av[2];
            loadBfrag(Bv, buf, kk2);
            loadA(Av, kk);
#pragma unroll
            for (int m = 0; m < 2; ++m)
#pragma unroll
                for (int n = 0; n < 4; ++n)
                    acc[m][n] = __builtin_amdgcn_mfma_f32_16x16x32_bf16(Av[m], Bv[n], acc[m][n], 0, 0, 0);
        }
        BARRIER();
        stageB(p + 2, buf);
    }

    // ---- epilogue: bias, LN stats, LN+ReLU store, optional fused dur ----
#pragma unroll
    for (int m = 0; m < 2; ++m)
#pragma unroll
        for (int q = 0; q < 4; ++q) {
            float s = 0.f, s2 = 0.f;
#pragma unroll
            for (int n = 0; n < 4; ++n) {
                float v2 = acc[m][n][q] + bv[n];
                acc[m][n][q] = v2;
                s += v2; s2 += v2 * v2;
            }
#pragma unroll
            for (int o = 1; o < 16; o <<= 1) { s += __shfl_xor(s, o); s2 += __shfl_xor(s2, o); }
            int row = rg * 32 + m * 16 + (l >> 4) * 4 + q;   // C/D: col=l&15, row=(l>>4)*4+q
            if ((l & 15) == 0) { red[row][fg * 2] = s; red[row][fg * 2 + 1] = s2; }
        }
    __syncthreads();                                     // barrier #2+2*PHASES

#pragma unroll
    for (int m = 0; m < 2; ++m)
#pragma unroll
        for (int q = 0; q < 4; ++q) {
            int row = rg * 32 + m * 16 + (l >> 4) * 4 + q;
            float s  = red[row][0] + red[row][2] + red[row][4] + red[row][6];
            float s2 = red[row][1] + red[row][3] + red[row][5] + red[row][7];
            float mu  = s * (1.f / F_);
            float var = s2 * (1.f / F_) - mu * mu;
            float rs  = rsqrtf(var + EPS_);
            size_t rbase = ((size_t)(b * T_ + t0 + row)) * F_;
            float part = 0.f;
#pragma unroll
            for (int n = 0; n < 4; ++n) {
                float y = (acc[m][n][q] - mu) * rs * gv[n] + bev[n];
                y = fmaxf(y, 0.f);
                out[rbase + fg * 64 + n * 16 + (l & 15)] = f2bf(y);
                if constexpr (FUSE_DUR) part = fmaf(y, wlv[n], part);
            }
            if constexpr (FUSE_DUR) {
#pragma unroll
                for (int o = 1; o < 16; o <<= 1) part += __shfl_xor(part, o);
                if ((l & 15) == 0) redD[row][fg] = part;
            }
        }

    if constexpr (FUSE_DUR) {
        __syncthreads();                                 // final barrier
        if (threadIdx.x < MT) {
            float s = redD[threadIdx.x][0] + redD[threadIdx.x][1]
                    + redD[threadIdx.x][2] + redD[threadIdx.x][3] + blv;
            dur[(size_t)b * T_ + t0 + threadIdx.x] = fmaxf(s, 0.f);
        }
    }
}

extern "C" void kernel_launch(void* const* d_in, const int* in_sizes, int n_in,
                              void* d_out, int out_size, void* d_ws, size_t ws_size,
                              hipStream_t stream)
{
    const float* x      = (const float*)d_in[0];
    const int*   target = (const int*)d_in[1];
    const float* w1  = (const float*)d_in[3];
    const float* b1  = (const float*)d_in[4];
    const float* g1  = (const float*)d_in[5];
    const float* be1 = (const float*)d_in[6];
    const float* w2  = (const float*)d_in[7];
    const float* b2  = (const float*)d_in[8];
    const float* g2  = (const float*)d_in[9];
    const float* be2 = (const float*)d_in[10];
    const float* wl  = (const float*)d_in[11];
    const float* bl  = (const float*)d_in[12];

    float* out = (float*)d_out;                        // (B, MEL, D)
    float* dur = out + (size_t)B_ * MEL * D_;          // (B, T)

    char* ws = (char*)d_ws;
    unsigned short* w1T = (unsigned short*)ws;         ws += (size_t)F_ * (3 * D_) * 2;
    unsigned short* w2T = (unsigned short*)ws;         ws += (size_t)F_ * (3 * F_) * 2;
    unsigned short* h1  = (unsigned short*)ws;         ws += (size_t)B_ * T_ * F_ * 2;
    unsigned short* h2  = (unsigned short*)ws;         ws += (size_t)B_ * T_ * F_ * 2;
    int*            gidx = (int*)ws;                   // B_*MEL ints

    prep_kernel<<<PREP_WBLOCKS + B_, 256, 0, stream>>>(w1, w2, target, w1T, w2T, gidx);

    // gather rows: 5/8 with conv1 (40/wave), 3/8 with conv2 (24/wave)
    conv_gather_kernel<D_, float, false, 40, 0><<<B_ * (T_ / 64), 1024, 0, stream>>>(
        x, w1T, b1, g1, be1, h1, nullptr, nullptr, nullptr, x, gidx, out);
    conv_gather_kernel<F_, unsigned short, true, 24, 81920><<<B_ * (T_ / 64), 1024, 0, stream>>>(
        h1, w2T, b2, g2, be2, h2, wl, bl, dur, x, gidx, out);
}

// Round 7
// 95.229 us; speedup vs baseline: 4.8972x; 1.1402x over previous
//
#include <hip/hip_runtime.h>
#include <type_traits>

#define B_   32
#define T_   512
#define D_   512
#define F_   256
#define MEL  4096
#define EPS_ 1e-5f

typedef __attribute__((ext_vector_type(8))) short bf16x8;
typedef __attribute__((ext_vector_type(4))) float f32x4;

#define GLL16(gp, lp) \
    __builtin_amdgcn_global_load_lds((const __attribute__((address_space(1))) void*)(gp), \
                                     (__attribute__((address_space(3))) void*)(lp), 16, 0, 0)
#define BARRIER() do { asm volatile("" ::: "memory"); __builtin_amdgcn_s_barrier(); \
                       asm volatile("" ::: "memory"); } while (0)
#define MEMPIN() asm volatile("" ::: "memory")

__device__ inline unsigned short f2bf(float f) {
    unsigned u = __float_as_uint(f);
    unsigned r = (u + 0x7fff + ((u >> 16) & 1)) >> 16;   // RNE
    return (unsigned short)r;
}

// ---------------------------------------------------------------------------
// prep: weight transpose/convert (blocks 0..2303) + per-batch cumsum & idx
// precompute (blocks 2304..2335). gidx[b][pos] = source row, or -1 (masked).
// ---------------------------------------------------------------------------
#define PREP_WBLOCKS 2304   // (3*D_*F_ + 3*F_*F_) / 256

__global__ __launch_bounds__(256)
void prep_kernel(const float* __restrict__ w1, const float* __restrict__ w2,
                 const int* __restrict__ tgt,
                 unsigned short* __restrict__ w1T, unsigned short* __restrict__ w2T,
                 int* __restrict__ gidx)
{
    __shared__ int lcum[T_];
    __shared__ int wsum[4];

    int bid = blockIdx.x;
    int tid = threadIdx.x;
    if (bid < PREP_WBLOCKS) {
        int idx = bid * 256 + tid;
        if (idx < 3 * D_ * F_) {
            int kk = idx / F_, f = idx % F_;
            w1T[(size_t)f * (3 * D_) + kk] = f2bf(w1[idx]);
        } else {
            int j = idx - 3 * D_ * F_;
            int kk = j / F_, f = j % F_;
            w2T[(size_t)f * (3 * F_) + kk] = f2bf(w2[j]);
        }
        return;
    }

    int b = bid - PREP_WBLOCKS;
    int t0 = tid * 2;
    int a0 = tgt[b * T_ + t0], a1 = tgt[b * T_ + t0 + 1];
    int lane = tid & 63, w = tid >> 6;
    int v = a0 + a1;
#pragma unroll
    for (int o = 1; o < 64; o <<= 1) { int u = __shfl_up(v, o); if (lane >= o) v += u; }
    if (lane == 63) wsum[w] = v;
    __syncthreads();
    int base = 0;
#pragma unroll
    for (int i = 0; i < 4; ++i) if (i < w) base += wsum[i];
    int incl = base + v;
    lcum[t0]     = incl - a1;
    lcum[t0 + 1] = incl;
    __syncthreads();

    int total = lcum[T_ - 1];
#pragma unroll
    for (int k = 0; k < MEL / 256; ++k) {
        int pos = tid + k * 256;
        int lo = 0, hi = T_;
        while (lo < hi) { int mid = (lo + hi) >> 1; if (lcum[mid] <= pos) lo = mid + 1; else hi = mid; }
        gidx[b * MEL + pos] = (pos < total) ? min(lo, T_ - 1) : -1;
    }
}

// ---------------------------------------------------------------------------
// Fused conv1d(K=3,SAME)+bias+LN+ReLU via bf16 MFMA, with the length-regulator
// gather integrated into the SAME waves' counted-vmcnt pipeline (no extra
// barriers, no wave-role split). 512 thr (8 waves = 2rg x 4fg), MT=64 rows.
// Per phase body (after 2nd barrier): [store set_p][load set_{p+3}][gll B_{p+2}]
// vmcnt ledger (verified): baseline 0 -> prologue [gidx|B0|B1|s0|s1|s2] ->
// X(0)=8, X(1)=16, steady X=12, gll-only region X=4.
// GPHASES = phases carrying gather work (2 rows/wave each); GBASE = first row.
// ---------------------------------------------------------------------------
template<int IN_D, typename InT, bool FUSE_DUR, int GPHASES, int GBASE>
__global__ __launch_bounds__(512)
void conv_mfma_kernel(const InT* __restrict__ x, const unsigned short* __restrict__ wT,
                      const float* __restrict__ bias, const float* __restrict__ gamma,
                      const float* __restrict__ beta, unsigned short* __restrict__ out,
                      const float* __restrict__ wl, const float* __restrict__ bl,
                      float* __restrict__ dur,
                      const float* __restrict__ xf, const int* __restrict__ gidx,
                      float* __restrict__ gout)
{
    constexpr int MT = 64;
    constexpr int KT = 3 * IN_D;
    constexpr int PHASES = KT / 64;                  // 24 (conv1) / 12 (conv2)

    __shared__ __align__(16) char xs_raw[(MT + 2) * IN_D * 2];
    __shared__ __align__(16) unsigned short xsB[2 * 16384];   // 2 x 32 KB B buffers
    __shared__ float red[MT][8];
    __shared__ float redD[MT][4];

    const int blocksPerBatch = T_ / MT;              // 8
    const int b  = blockIdx.x / blocksPerBatch;
    const int t0 = (blockIdx.x % blocksPerBatch) * MT;
    const int l  = threadIdx.x & 63;
    const int wv = threadIdx.x >> 6;                 // 0..7
    const int fg = wv & 3;
    const int rg = wv >> 2;

    // ---- stage A rows t0-1 .. t0+MT into LDS as bf16, swizzled ----
    constexpr int CH = (MT + 2) * IN_D / 8;
    for (int c = threadIdx.x; c < CH; c += 512) {
        int j  = c / (IN_D / 8);
        int d8 = (c % (IN_D / 8)) * 8;
        int t  = t0 - 1 + j;
        uint4 pk = make_uint4(0u, 0u, 0u, 0u);
        if (t >= 0 && t < T_) {
            if constexpr (std::is_same_v<InT, float>) {
                const float4* src = reinterpret_cast<const float4*>(&x[((size_t)b * T_ + t) * IN_D + d8]);
                float4 a0 = src[0], a1 = src[1];
                pk.x = (unsigned)f2bf(a0.x) | ((unsigned)f2bf(a0.y) << 16);
                pk.y = (unsigned)f2bf(a0.z) | ((unsigned)f2bf(a0.w) << 16);
                pk.z = (unsigned)f2bf(a1.x) | ((unsigned)f2bf(a1.y) << 16);
                pk.w = (unsigned)f2bf(a1.z) | ((unsigned)f2bf(a1.w) << 16);
            } else {
                pk = *reinterpret_cast<const uint4*>(&x[((size_t)b * T_ + t) * IN_D + d8]);
            }
        }
        int byte = ((j * IN_D + d8) * 2) ^ ((j & 7) << 4);
        *reinterpret_cast<uint4*>(&xs_raw[byte]) = pk;
    }

    float bv[4], gv[4], bev[4], wlv[4];
#pragma unroll
    for (int n = 0; n < 4; ++n) {
        int f = fg * 64 + n * 16 + (l & 15);
        bv[n] = bias[f]; gv[n] = gamma[f]; bev[n] = beta[f];
        if constexpr (FUSE_DUR) wlv[n] = wl[f];
    }
    float blv = FUSE_DUR ? bl[0] : 0.f;

    asm volatile("s_waitcnt vmcnt(0)" ::: "memory");   // explicit baseline drain
    __syncthreads();

    // ---- gather assignment: 2*GPHASES consecutive rows per wave ----
    constexpr int GROWS = 2 * GPHASES;
    const int rbase = GBASE + (blockIdx.x * 8 + wv) * GROWS;
    int gidxv = gidx[rbase + min(l, GROWS - 1)];       // 1 vmem op
    MEMPIN();

    // ---- B staging: [256 f][8 kg][8 k], slot XOR kg^(f&7); gll dest linear ----
    const int sbase = wv * 4;
    auto stageB = [&](int ph, int buf) {
        int p = ph < PHASES ? ph : PHASES - 1;
        unsigned short* lb = &xsB[buf * 16384];
#pragma unroll
        for (int i = 0; i < 4; ++i) {
            int s = sbase + i;
            int c = s * 64 + l;
            int f = c >> 3;
            int kg = (c & 7) ^ (f & 7);
            const unsigned short* src = wT + (size_t)f * KT + p * 64 + kg * 8;
            GLL16(src, lb + s * 512);
        }
    };
    auto loadBfrag = [&](bf16x8* dst, int buf, int kk2) {
#pragma unroll
        for (int n = 0; n < 4; ++n) {
            int f  = fg * 64 + n * 16 + (l & 15);
            int kg = kk2 * 4 + (l >> 4);
            dst[n] = *reinterpret_cast<const bf16x8*>(&xsB[buf * 16384 + f * 64 + ((kg ^ (f & 7)) * 8)]);
        }
    };
    const int k_lane = (l >> 4) * 8;
    auto loadA = [&](bf16x8* dst, int kk) {
        int kp = kk / IN_D;
        int dbase = (kk % IN_D) + k_lane;
#pragma unroll
        for (int m = 0; m < 2; ++m) {
            int j = rg * 32 + m * 16 + (l & 15) + kp;
            int byte = ((j * IN_D + dbase) * 2) ^ ((j & 7) << 4);
            dst[m] = *reinterpret_cast<const bf16x8*>(&xs_raw[byte]);
        }
    };

    // gather set load/store: 2 rows, each row = 2 dwordx4 per lane (contiguous KB halves)
    float4 ga[3][2][2];
    auto loadSet = [&](int slot, int s) {
#pragma unroll
        for (int i = 0; i < 2; ++i) {
            int li = min(2 * s + i, GROWS - 1);        // clamp for dummy tail sets
            int ix = __shfl(gidxv, li);
            int r  = rbase + li;
            const float* src = xf + ((size_t)(r >> 12) * T_ + max(ix, 0)) * D_ + l * 4;
            ga[slot][i][0] = *reinterpret_cast<const float4*>(src);
            ga[slot][i][1] = *reinterpret_cast<const float4*>(src + 256);
        }
    };
    auto storeSet = [&](int slot, int s) {
#pragma unroll
        for (int i = 0; i < 2; ++i) {
            int li = 2 * s + i;                        // s < GPHASES here
            int ix = __shfl(gidxv, li);
            int r  = rbase + li;
            float4 a = ga[slot][i][0], c = ga[slot][i][1];
            if (ix < 0) { a = make_float4(0.f,0.f,0.f,0.f); c = make_float4(0.f,0.f,0.f,0.f); }
            float* d = gout + (size_t)r * D_ + l * 4;
            *reinterpret_cast<float4*>(d)       = a;
            *reinterpret_cast<float4*>(d + 256) = c;
        }
    };

    f32x4 acc[2][4];
#pragma unroll
    for (int m = 0; m < 2; ++m)
#pragma unroll
        for (int n = 0; n < 4; ++n) acc[m][n] = (f32x4){0.f, 0.f, 0.f, 0.f};

    // ---- prologue: pinned op groups [B0][B1][s0][s1][s2] ----
    stageB(0, 0);  MEMPIN();
    stageB(1, 1);  MEMPIN();
    loadSet(0, 0); MEMPIN();
    loadSet(1, 1); MEMPIN();
    loadSet(2, 2);

    // ---- phase loop (fully unrolled; X per ledger) ----
#pragma unroll
    for (int p = 0; p < PHASES; ++p) {
        if (p == 0)                asm volatile("s_waitcnt vmcnt(8)"  ::: "memory");
        else if (p == 1)           asm volatile("s_waitcnt vmcnt(16)" ::: "memory");
        else if (p < GPHASES + 1)  asm volatile("s_waitcnt vmcnt(12)" ::: "memory");
        else                       asm volatile("s_waitcnt vmcnt(4)"  ::: "memory");
        BARRIER();
        int buf = p & 1;
#pragma unroll
        for (int kk2 = 0; kk2 < 2; ++kk2) {
            int kk = p * 64 + kk2 * 32;
            bf16x8 Bv[4], Av[2];
            loadBfrag(Bv, buf, kk2);
            loadA(Av, kk);
#pragma unroll
            for (int m = 0; m < 2; ++m)
#pragma unroll
                for (int n = 0; n < 4; ++n)
                    acc[m][n] = __builtin_amdgcn_mfma_f32_16x16x32_bf16(Av[m], Bv[n], acc[m][n], 0, 0, 0);
        }
        BARRIER();
        // body: [st set_p][ld set_{p+3}][gll B_{p+2}]  (12 ops, or 4 in tail region)
        if (p < GPHASES) {
            storeSet(p % 3, p);
            loadSet(p % 3, p + 3);
        }
        stageB(p + 2, buf);
    }

    // ---- epilogue: bias, LN stats, LN+ReLU store, optional fused dur ----
#pragma unroll
    for (int m = 0; m < 2; ++m)
#pragma unroll
        for (int q = 0; q < 4; ++q) {
            float s = 0.f, s2 = 0.f;
#pragma unroll
            for (int n = 0; n < 4; ++n) {
                float v2 = acc[m][n][q] + bv[n];
                acc[m][n][q] = v2;
                s += v2; s2 += v2 * v2;
            }
#pragma unroll
            for (int o = 1; o < 16; o <<= 1) { s += __shfl_xor(s, o); s2 += __shfl_xor(s2, o); }
            int row = rg * 32 + m * 16 + (l >> 4) * 4 + q;   // C/D: col=l&15, row=(l>>4)*4+q
            if ((l & 15) == 0) { red[row][fg * 2] = s; red[row][fg * 2 + 1] = s2; }
        }
    __syncthreads();

#pragma unroll
    for (int m = 0; m < 2; ++m)
#pragma unroll
        for (int q = 0; q < 4; ++q) {
            int row = rg * 32 + m * 16 + (l >> 4) * 4 + q;
            float s  = red[row][0] + red[row][2] + red[row][4] + red[row][6];
            float s2 = red[row][1] + red[row][3] + red[row][5] + red[row][7];
            float mu  = s * (1.f / F_);
            float var = s2 * (1.f / F_) - mu * mu;
            float rs  = rsqrtf(var + EPS_);
            size_t rb2 = ((size_t)(b * T_ + t0 + row)) * F_;
            float part = 0.f;
#pragma unroll
            for (int n = 0; n < 4; ++n) {
                float y = (acc[m][n][q] - mu) * rs * gv[n] + bev[n];
                y = fmaxf(y, 0.f);
                out[rb2 + fg * 64 + n * 16 + (l & 15)] = f2bf(y);
                if constexpr (FUSE_DUR) part = fmaf(y, wlv[n], part);
            }
            if constexpr (FUSE_DUR) {
#pragma unroll
                for (int o = 1; o < 16; o <<= 1) part += __shfl_xor(part, o);
                if ((l & 15) == 0) redD[row][fg] = part;
            }
        }

    if constexpr (FUSE_DUR) {
        __syncthreads();
        if (threadIdx.x < MT) {
            float s = redD[threadIdx.x][0] + redD[threadIdx.x][1]
                    + redD[threadIdx.x][2] + redD[threadIdx.x][3] + blv;
            dur[(size_t)b * T_ + t0 + threadIdx.x] = fmaxf(s, 0.f);
        }
    }
}

extern "C" void kernel_launch(void* const* d_in, const int* in_sizes, int n_in,
                              void* d_out, int out_size, void* d_ws, size_t ws_size,
                              hipStream_t stream)
{
    const float* x      = (const float*)d_in[0];
    const int*   target = (const int*)d_in[1];
    const float* w1  = (const float*)d_in[3];
    const float* b1  = (const float*)d_in[4];
    const float* g1  = (const float*)d_in[5];
    const float* be1 = (const float*)d_in[6];
    const float* w2  = (const float*)d_in[7];
    const float* b2  = (const float*)d_in[8];
    const float* g2  = (const float*)d_in[9];
    const float* be2 = (const float*)d_in[10];
    const float* wl  = (const float*)d_in[11];
    const float* bl  = (const float*)d_in[12];

    float* out = (float*)d_out;                        // (B, MEL, D)
    float* dur = out + (size_t)B_ * MEL * D_;          // (B, T)

    char* ws = (char*)d_ws;
    unsigned short* w1T = (unsigned short*)ws;         ws += (size_t)F_ * (3 * D_) * 2;
    unsigned short* w2T = (unsigned short*)ws;         ws += (size_t)F_ * (3 * F_) * 2;
    unsigned short* h1  = (unsigned short*)ws;         ws += (size_t)B_ * T_ * F_ * 2;
    unsigned short* h2  = (unsigned short*)ws;         ws += (size_t)B_ * T_ * F_ * 2;
    int*            gidx = (int*)ws;                   // B_*MEL ints

    prep_kernel<<<PREP_WBLOCKS + B_, 256, 0, stream>>>(w1, w2, target, w1T, w2T, gidx);

    // conv1 carries gather rows 0..98303 (24 phases x 2 rows x 8 waves x 256 blocks),
    // conv2 carries rows 98304..131071 (first 8 of 12 phases).
    conv_mfma_kernel<D_, float, false, 24, 0><<<B_ * (T_ / 64), 512, 0, stream>>>(
        x, w1T, b1, g1, be1, h1, nullptr, nullptr, nullptr, x, gidx, out);
    conv_mfma_kernel<F_, unsigned short, true, 8, 98304><<<B_ * (T_ / 64), 512, 0, stream>>>(
        h1, w2T, b2, g2, be2, h2, wl, bl, dur, x, gidx, out);
}